// Round 8
// baseline (3788.931 us; speedup 1.0000x reference)
//
#include <hip/hip_runtime.h>
#include <hip/hip_bf16.h>

#define SORB  64
#define HID   512
#define BATCH 4096
#define N3H   1536   // 3*HID
#define KD    512    // GEMM K = HID
#define PI_F  3.14159265358979f

typedef _Float16 half8 __attribute__((ext_vector_type(8)));
typedef float    floatx4 __attribute__((ext_vector_type(4)));

// ---------- weight conversion: f32 -> f16 for the three big GEMM weights ----------
__global__ __launch_bounds__(256) void convw_kernel(
    const float* __restrict__ w0, const float* __restrict__ w1, const float* __restrict__ w2,
    _Float16* __restrict__ o0, _Float16* __restrict__ o1, _Float16* __restrict__ o2)
{
    const int i = blockIdx.x * 256 + threadIdx.x;
    if (i < N3H * KD) {
        o0[i] = (_Float16)w0[i];
        o1[i] = (_Float16)w1[i];
        o2[i] = (_Float16)w2[i];
    }
}

// ---------- MFMA GEMM: O[M,N](f16) = A[M,K](f16) * W[N,K]^T(f16) ----------
// M=4096, N=1536, K=512. 128x128 tile, BK=32, 4 waves (2x2), 16x16x32 MFMA.
// Verified bit-identical to reference VALU GEMM (rounds 4==5).
// Reg-staged LDS with 16B-unit XOR swizzle: phys unit (row,pu) holds logical
// (row, pu ^ ((row>>1)&3)).
__global__ __launch_bounds__(256) void gemm_kernel(
    const _Float16* __restrict__ A0, const _Float16* __restrict__ W0, _Float16* __restrict__ O0,
    const _Float16* __restrict__ A1, const _Float16* __restrict__ W1, _Float16* __restrict__ O1)
{
    const _Float16* A = blockIdx.z ? A1 : A0;
    const _Float16* W = blockIdx.z ? W1 : W0;
    _Float16*       O = blockIdx.z ? O1 : O0;

    __shared__ __align__(16) _Float16 As[128 * 32];
    __shared__ __align__(16) _Float16 Ws[128 * 32];

    const int tid  = threadIdx.x;
    const int lane = tid & 63;
    const int wid  = tid >> 6;
    const int wm   = wid >> 1, wn = wid & 1;
    const int m0   = blockIdx.y * 128;
    const int n0   = blockIdx.x * 128;

    floatx4 acc[4][4];
    const floatx4 z4 = {0.f, 0.f, 0.f, 0.f};
#pragma unroll
    for (int i = 0; i < 4; ++i)
#pragma unroll
        for (int j = 0; j < 4; ++j) acc[i][j] = z4;

    const int p0 = tid,       row0 = p0 >> 2, u0 = (p0 & 3) ^ ((row0 >> 1) & 3);
    const int p1 = tid + 256, row1 = p1 >> 2, u1 = (p1 & 3) ^ ((row1 >> 1) & 3);
    const _Float16* a_src0 = A + (size_t)(m0 + row0) * KD + u0 * 8;
    const _Float16* a_src1 = A + (size_t)(m0 + row1) * KD + u1 * 8;
    const _Float16* w_src0 = W + (size_t)(n0 + row0) * KD + u0 * 8;
    const _Float16* w_src1 = W + (size_t)(n0 + row1) * KD + u1 * 8;
    uint4* asl = (uint4*)As;
    uint4* wsl = (uint4*)Ws;

    int aoff[4], woff[4];
    const int ku = lane >> 4;
#pragma unroll
    for (int i = 0; i < 4; ++i) {
        const int ra = wm * 64 + i * 16 + (lane & 15);
        aoff[i] = ra * 32 + ((ku ^ ((ra >> 1) & 3)) * 8);
        const int rw = wn * 64 + i * 16 + (lane & 15);
        woff[i] = rw * 32 + ((ku ^ ((rw >> 1) & 3)) * 8);
    }

    for (int kt = 0; kt < 16; ++kt) {
        const int k0 = kt * 32;
        const uint4 ra0 = *(const uint4*)(a_src0 + k0);
        const uint4 ra1 = *(const uint4*)(a_src1 + k0);
        const uint4 rw0 = *(const uint4*)(w_src0 + k0);
        const uint4 rw1 = *(const uint4*)(w_src1 + k0);
        __syncthreads();
        asl[p0] = ra0; asl[p1] = ra1;
        wsl[p0] = rw0; wsl[p1] = rw1;
        __syncthreads();
        half8 af[4], wf[4];
#pragma unroll
        for (int i = 0; i < 4; ++i) af[i] = *(const half8*)(As + aoff[i]);
#pragma unroll
        for (int i = 0; i < 4; ++i) wf[i] = *(const half8*)(Ws + woff[i]);
#pragma unroll
        for (int mi = 0; mi < 4; ++mi)
#pragma unroll
            for (int ni = 0; ni < 4; ++ni)
                acc[mi][ni] = __builtin_amdgcn_mfma_f32_16x16x32_f16(af[mi], wf[ni], acc[mi][ni], 0, 0, 0);
    }

#pragma unroll
    for (int mi = 0; mi < 4; ++mi)
#pragma unroll
        for (int ni = 0; ni < 4; ++ni) {
            const int col   = n0 + wn * 64 + ni * 16 + (lane & 15);
            const int rbase = m0 + wm * 64 + mi * 16 + (lane >> 4) * 4;
#pragma unroll
            for (int j = 0; j < 4; ++j)
                O[(size_t)(rbase + j) * N3H + col] = (_Float16)acc[mi][ni][j];
        }
}

__device__ __forceinline__ float sigmoidf_(float x) { return 1.f / (1.f + __expf(-x)); }
__device__ __forceinline__ float tanhf_(float x) {
    x = fminf(fmaxf(x, -15.f), 15.f);
    const float e2 = __expf(2.f * x);
    return (e2 - 1.f) / (e2 + 1.f);
}

// GRU layer-0 gates: h0n = (1-z)*n + z*h0 ; gi = one-hot-selected column of W_ih0 (f32 direct)
__global__ __launch_bounds__(256) void gates0_kernel(
    const _Float16* __restrict__ gh, const float* __restrict__ Wih0,
    const int* __restrict__ bits, float* __restrict__ h0f, _Float16* __restrict__ h0h, int step)
{
    const int idx = blockIdx.x * 256 + threadIdx.x;  // b*512 + j
    const int b = idx >> 9, j = idx & 511;
    float gir = 0.f, giz = 0.f, gin = 0.f;
    if (step > 0) {
        const int t = bits[b * SORB + step - 1];
        gir = Wih0[j * 2 + t];
        giz = Wih0[(HID + j) * 2 + t];
        gin = Wih0[(2 * HID + j) * 2 + t];
    }
    const _Float16* g = gh + (size_t)b * N3H;
    const float r = sigmoidf_(gir + (float)g[j]);
    const float z = sigmoidf_(giz + (float)g[HID + j]);
    const float n = tanhf_(gin + r * (float)g[2 * HID + j]);
    const float h = h0f[idx];
    const float hn = (1.f - z) * n + z * h;
    h0f[idx] = hn;
    h0h[idx] = (_Float16)hn;
}

// GRU layer-1 gates + heads + accumulation. One block (256 thr) per batch row.
__global__ __launch_bounds__(256) void gates1_kernel(
    const _Float16* __restrict__ gi, const _Float16* __restrict__ gh,
    float* __restrict__ h1f, _Float16* __restrict__ h1h,
    const float* __restrict__ Wamp, const float* __restrict__ bamp,
    const float* __restrict__ Wph,  const float* __restrict__ bph,
    const int* __restrict__ bits,
    float* __restrict__ amp, float* __restrict__ phase,
    int* __restrict__ nup, int* __restrict__ ndn,
    float* __restrict__ out, int step)   // f32 output!
{
    const int b = blockIdx.x, t = threadIdx.x;
    const _Float16* gib = gi + (size_t)b * N3H;
    const _Float16* ghb = gh + (size_t)b * N3H;
    float d0 = 0.f, d1 = 0.f, d2 = 0.f, d3 = 0.f;
#pragma unroll
    for (int jj = 0; jj < 2; ++jj) {
        const int j = t + jj * 256;
        const float r = sigmoidf_((float)gib[j] + (float)ghb[j]);
        const float z = sigmoidf_((float)gib[HID + j] + (float)ghb[HID + j]);
        const float n = tanhf_((float)gib[2 * HID + j] + r * (float)ghb[2 * HID + j]);
        const size_t hidx = (size_t)b * HID + j;
        const float h = h1f[hidx];
        const float hn = (1.f - z) * n + z * h;
        h1f[hidx] = hn;
        h1h[hidx] = (_Float16)hn;
        d0 += hn * Wamp[j];
        d1 += hn * Wamp[HID + j];
        d2 += hn * Wph[j];
        d3 += hn * Wph[HID + j];
    }
    __shared__ float red[4][256];
    red[0][t] = d0; red[1][t] = d1; red[2][t] = d2; red[3][t] = d3;
    __syncthreads();
    for (int s = 128; s > 0; s >>= 1) {
        if (t < s) {
            red[0][t] += red[0][t + s]; red[1][t] += red[1][t + s];
            red[2][t] += red[2][t + s]; red[3][t] += red[3][t + s];
        }
        __syncthreads();
    }
    if (t == 0) {
        const float a0 = red[0][0] + bamp[0];
        const float a1 = red[1][0] + bamp[1];
        const float mx = fmaxf(a0, a1);
        const float e0 = __expf(a0 - mx), e1 = __expf(a1 - mx);
        const float inv = 1.f / (e0 + e1);
        float ya0 = sqrtf(e0 * inv), ya1 = sqrtf(e1 * inv);
        const float p0 = red[2][0] + bph[0];
        const float p1 = red[3][0] + bph[1];
        const float yp0 = PI_F * p0 / (1.f + fabsf(p0));
        const float yp1 = PI_F * p1 / (1.f + fabsf(p1));
        const int even = ((step & 1) == 0);
        const int cnt = even ? nup[b] : ndn[b];
        if (step >= 32) {  // MIN_I
            const int lower = (step >> 1) - 16;
            const float m0v = (cnt > lower) ? ya0 : 0.f;
            const float m1v = (cnt < 16) ? ya1 : 0.f;
            const float nrm = sqrtf(m0v * m0v + m1v * m1v + 1e-12f);
            ya0 = m0v / nrm; ya1 = m1v / nrm;
        }
        const int bi = bits[b * SORB + step];
        const float na = amp[b] * (bi ? ya1 : ya0);
        const float np = phase[b] + (bi ? yp1 : yp0);
        amp[b] = na; phase[b] = np;
        if (bi) { if (even) nup[b] = cnt + 1; else ndn[b] = cnt + 1; }
        if (step == SORB - 1) {
            out[b * 2 + 0] = na;     // f32 output, (B,2) row-major
            out[b * 2 + 1] = np;
        }
    }
}

__global__ __launch_bounds__(256) void init_kernel(
    float* __restrict__ amp, float* __restrict__ phase,
    int* __restrict__ nup, int* __restrict__ ndn)
{
    const int i = blockIdx.x * 256 + threadIdx.x;
    if (i < BATCH) { amp[i] = 1.f; phase[i] = 0.f; nup[i] = 0; ndn[i] = 0; }
}

extern "C" void kernel_launch(void* const* d_in, const int* in_sizes, int n_in,
                              void* d_out, int out_size, void* d_ws, size_t ws_size,
                              hipStream_t stream) {
    const int*   bits = (const int*)d_in[0];
    const float* Wih0 = (const float*)d_in[1];
    const float* Whh0 = (const float*)d_in[2];
    const float* Wih1 = (const float*)d_in[3];
    const float* Whh1 = (const float*)d_in[4];
    const float* Wamp = (const float*)d_in[5];
    const float* bamp = (const float*)d_in[6];
    const float* Wph  = (const float*)d_in[7];
    const float* bph  = (const float*)d_in[8];
    float* out = (float*)d_out;   // reference output dtype = float32

    char* ws = (char*)d_ws;
    size_t off = 0;
    auto alloc = [&](size_t bytes) {
        void* p = ws + off;
        off = (off + bytes + 255) & ~(size_t)255;
        return p;
    };
    _Float16* wh0 = (_Float16*)alloc((size_t)N3H * KD * 2);
    _Float16* wi1 = (_Float16*)alloc((size_t)N3H * KD * 2);
    _Float16* wh1 = (_Float16*)alloc((size_t)N3H * KD * 2);
    float*    h0f = (float*)alloc((size_t)BATCH * HID * 4);
    float*    h1f = (float*)alloc((size_t)BATCH * HID * 4);
    _Float16* h0h = (_Float16*)alloc((size_t)BATCH * HID * 2);
    _Float16* h1h = (_Float16*)alloc((size_t)BATCH * HID * 2);
    _Float16* gA  = (_Float16*)alloc((size_t)BATCH * N3H * 2);
    _Float16* gB  = (_Float16*)alloc((size_t)BATCH * N3H * 2);
    float*    amp   = (float*)alloc((size_t)BATCH * 4);
    float*    phase = (float*)alloc((size_t)BATCH * 4);
    int*      nup   = (int*)alloc((size_t)BATCH * 4);
    int*      ndn   = (int*)alloc((size_t)BATCH * 4);

    hipMemsetAsync(h0f, 0, (size_t)BATCH * HID * 4, stream);
    hipMemsetAsync(h1f, 0, (size_t)BATCH * HID * 4, stream);
    hipMemsetAsync(h0h, 0, (size_t)BATCH * HID * 2, stream);
    hipMemsetAsync(h1h, 0, (size_t)BATCH * HID * 2, stream);
    convw_kernel<<<(N3H * KD + 255) / 256, 256, 0, stream>>>(Whh0, Wih1, Whh1, wh0, wi1, wh1);
    init_kernel<<<BATCH / 256, 256, 0, stream>>>(amp, phase, nup, ndn);

    dim3 g1(N3H / 128, BATCH / 128, 1);
    dim3 g2(N3H / 128, BATCH / 128, 2);
    for (int i = 0; i < SORB; ++i) {
        gemm_kernel<<<g1, 256, 0, stream>>>(h0h, wh0, gA, h0h, wh0, gA);
        gates0_kernel<<<BATCH * HID / 256, 256, 0, stream>>>(gA, Wih0, bits, h0f, h0h, i);
        gemm_kernel<<<g2, 256, 0, stream>>>(h0h, wi1, gA, h1h, wh1, gB);
        gates1_kernel<<<BATCH, 256, 0, stream>>>(gA, gB, h1f, h1h, Wamp, bamp, Wph, bph,
                                                 bits, amp, phase, nup, ndn, out, i);
    }
}